// Round 10
// baseline (689.895 us; speedup 1.0000x reference)
//
#include <hip/hip_runtime.h>

// ---------------------------------------------------------------------------
// MagNet link prediction forward, f32 (16-bit quant of propagated streams
// fails: complex-ReLU mask flips amplify tiny hr errors — rounds 3/4).
// Gather (CSR), telescoped Chebyshev: out = x@(W0-W2)+b + prop(g1+2*prop(g2)).
// Round 10: ORCHESTRATION — deg_count (latency-bound atomics, 0.2% VALU) is
// independent of layer-1 GEMM (VALU-bound), so they share ONE dispatch
// (blocks [0,eb) = deg, [eb,eb+mb) = gemm); scan2 folded into scan3.
// Sparse passes unchanged: pinned at the ~3.65 TB/s random-gather wall
// (invariant across 5 structures, rounds 2..9).
// ---------------------------------------------------------------------------

__device__ __forceinline__ float4 ld4(const float* __restrict__ p) {
  return *reinterpret_cast<const float4*>(p);
}
__device__ __forceinline__ float2 ld2(const float* __restrict__ p) {
  return *reinterpret_cast<const float2*>(p);
}

// ---- fused: deg+count packed atomics  ||  6-stream GEMM (layer 1) -----------
template <int K>
__global__ __launch_bounds__(256) void k_fuse_deg_gemm(
    const int* __restrict__ u, const int* __restrict__ v,
    const float* __restrict__ w, unsigned long long* __restrict__ dc, int E,
    int ebN,
    const float* __restrict__ Ar, const float* __restrict__ Ai,
    const float* __restrict__ W,  // [3][K][64]
    const float* __restrict__ bias,
    float* __restrict__ P1, float* __restrict__ P2,
    float* __restrict__ Hr, float* __restrict__ Hi, int M) {
  __shared__ float Asr[32][36];
  __shared__ float Asi[32][36];
  __shared__ float Ws1[32][64];
  __shared__ float Ws2[32][64];
  __shared__ float Wsm[32][64];
  if (blockIdx.x < (unsigned)ebN) {
    // ---- degree+count: one packed 64-bit atomic per endpoint ----
    int e = blockIdx.x * 256 + threadIdx.x;
    if (e >= E) return;
    float hw = 0.5f * w[e];
    unsigned fx = __float2uint_rn(hw * 16777216.f);  // 2^24 fixed point
    unsigned long long pk = (1ULL << 32) | (unsigned long long)fx;
    atomicAdd(&dc[u[e]], pk);
    atomicAdd(&dc[v[e]], pk);
    return;
  }
  // ---- GEMM: BM=32, BK=32, A+W in LDS ----
  const int bx = blockIdx.x - ebN;
  const int t = threadIdx.x;
  const int r0 = bx * 32;
  const int tc = t & 15, tr = t >> 4;
  const float* W0 = W;
  const float* W1 = W + (size_t)K * 64;
  const float* W2 = W + (size_t)2 * K * 64;
  float a1r[2][4] = {}, a1i[2][4] = {}, a2r[2][4] = {}, a2i[2][4] = {};
  float amr[2][4] = {}, ami[2][4] = {};
  for (int k0 = 0; k0 < K; k0 += 32) {
    {  // A tile: 32 rows x 8 float4, one per thread per array
      int row = t >> 3, c4 = t & 7;
      int gr = r0 + row;
      float4 fr = make_float4(0.f, 0.f, 0.f, 0.f), fi = fr;
      if (gr < M) {
        fr = ld4(&Ar[(size_t)gr * K + k0 + c4 * 4]);
        fi = ld4(&Ai[(size_t)gr * K + k0 + c4 * 4]);
      }
      *reinterpret_cast<float4*>(&Asr[row][c4 * 4]) = fr;
      *reinterpret_cast<float4*>(&Asi[row][c4 * 4]) = fi;
    }
    for (int li = t; li < 512; li += 256) {  // W tiles: 32 rows x 16 f4 each
      int row = li >> 4, c4 = li & 15;
      size_t woff = (size_t)(k0 + row) * 64 + c4 * 4;
      float4 w1 = ld4(&W1[woff]);
      float4 w2 = ld4(&W2[woff]);
      float4 w0 = ld4(&W0[woff]);
      *reinterpret_cast<float4*>(&Ws1[row][c4 * 4]) = w1;
      *reinterpret_cast<float4*>(&Ws2[row][c4 * 4]) = w2;
      *reinterpret_cast<float4*>(&Wsm[row][c4 * 4]) =
          make_float4(w0.x - w2.x, w0.y - w2.y, w0.z - w2.z, w0.w - w2.w);
    }
    __syncthreads();
#pragma unroll 4
    for (int k = 0; k < 32; ++k) {
      float4 b1 = *reinterpret_cast<const float4*>(&Ws1[k][tc * 4]);
      float4 b2 = *reinterpret_cast<const float4*>(&Ws2[k][tc * 4]);
      float4 bm = *reinterpret_cast<const float4*>(&Wsm[k][tc * 4]);
#pragma unroll
      for (int i = 0; i < 2; ++i) {
        float ar = Asr[tr * 2 + i][k], ai = Asi[tr * 2 + i][k];
        a1r[i][0] += ar * b1.x; a1r[i][1] += ar * b1.y; a1r[i][2] += ar * b1.z; a1r[i][3] += ar * b1.w;
        a1i[i][0] += ai * b1.x; a1i[i][1] += ai * b1.y; a1i[i][2] += ai * b1.z; a1i[i][3] += ai * b1.w;
        a2r[i][0] += ar * b2.x; a2r[i][1] += ar * b2.y; a2r[i][2] += ar * b2.z; a2r[i][3] += ar * b2.w;
        a2i[i][0] += ai * b2.x; a2i[i][1] += ai * b2.y; a2i[i][2] += ai * b2.z; a2i[i][3] += ai * b2.w;
        amr[i][0] += ar * bm.x; amr[i][1] += ar * bm.y; amr[i][2] += ar * bm.z; amr[i][3] += ar * bm.w;
        ami[i][0] += ai * bm.x; ami[i][1] += ai * bm.y; ami[i][2] += ai * bm.z; ami[i][3] += ai * bm.w;
      }
    }
    __syncthreads();
  }
  float b0 = bias[tc * 4 + 0], bb1 = bias[tc * 4 + 1];
  float b2v = bias[tc * 4 + 2], b3 = bias[tc * 4 + 3];
#pragma unroll
  for (int i = 0; i < 2; ++i) {
    int gr = r0 + tr * 2 + i;
    if (gr >= M) continue;
    size_t pb = (size_t)gr * 128 + tc * 8;  // feature pairs f=4tc..4tc+3
    *reinterpret_cast<float4*>(&P1[pb]) =
        make_float4(a1r[i][0], a1i[i][0], a1r[i][1], a1i[i][1]);
    *reinterpret_cast<float4*>(&P1[pb + 4]) =
        make_float4(a1r[i][2], a1i[i][2], a1r[i][3], a1i[i][3]);
    *reinterpret_cast<float4*>(&P2[pb]) =
        make_float4(a2r[i][0], a2i[i][0], a2r[i][1], a2i[i][1]);
    *reinterpret_cast<float4*>(&P2[pb + 4]) =
        make_float4(a2r[i][2], a2i[i][2], a2r[i][3], a2i[i][3]);
    size_t hb = (size_t)gr * 64 + tc * 4;
    *reinterpret_cast<float4*>(&Hr[hb]) =
        make_float4(amr[i][0] - ami[i][0] + b0, amr[i][1] - ami[i][1] + bb1,
                    amr[i][2] - ami[i][2] + b2v, amr[i][3] - ami[i][3] + b3);
    *reinterpret_cast<float4*>(&Hi[hb]) =
        make_float4(amr[i][0] + ami[i][0] + b0, amr[i][1] + ami[i][1] + bb1,
                    amr[i][2] + ami[i][2] + b2v, amr[i][3] + ami[i][3] + b3);
  }
}

// ---- standalone GEMM (layer 2) ----------------------------------------------
template <int K>
__global__ __launch_bounds__(256) void k_gemmF(
    const float* __restrict__ Ar, const float* __restrict__ Ai,
    const float* __restrict__ W, const float* __restrict__ bias,
    float* __restrict__ P1, float* __restrict__ P2,
    float* __restrict__ Hr, float* __restrict__ Hi, int M) {
  __shared__ float Asr[32][36];
  __shared__ float Asi[32][36];
  __shared__ float Ws1[32][64];
  __shared__ float Ws2[32][64];
  __shared__ float Wsm[32][64];
  const int t = threadIdx.x;
  const int r0 = blockIdx.x * 32;
  const int tc = t & 15, tr = t >> 4;
  const float* W0 = W;
  const float* W1 = W + (size_t)K * 64;
  const float* W2 = W + (size_t)2 * K * 64;
  float a1r[2][4] = {}, a1i[2][4] = {}, a2r[2][4] = {}, a2i[2][4] = {};
  float amr[2][4] = {}, ami[2][4] = {};
  for (int k0 = 0; k0 < K; k0 += 32) {
    {
      int row = t >> 3, c4 = t & 7;
      int gr = r0 + row;
      float4 fr = make_float4(0.f, 0.f, 0.f, 0.f), fi = fr;
      if (gr < M) {
        fr = ld4(&Ar[(size_t)gr * K + k0 + c4 * 4]);
        fi = ld4(&Ai[(size_t)gr * K + k0 + c4 * 4]);
      }
      *reinterpret_cast<float4*>(&Asr[row][c4 * 4]) = fr;
      *reinterpret_cast<float4*>(&Asi[row][c4 * 4]) = fi;
    }
    for (int li = t; li < 512; li += 256) {
      int row = li >> 4, c4 = li & 15;
      size_t woff = (size_t)(k0 + row) * 64 + c4 * 4;
      float4 w1 = ld4(&W1[woff]);
      float4 w2 = ld4(&W2[woff]);
      float4 w0 = ld4(&W0[woff]);
      *reinterpret_cast<float4*>(&Ws1[row][c4 * 4]) = w1;
      *reinterpret_cast<float4*>(&Ws2[row][c4 * 4]) = w2;
      *reinterpret_cast<float4*>(&Wsm[row][c4 * 4]) =
          make_float4(w0.x - w2.x, w0.y - w2.y, w0.z - w2.z, w0.w - w2.w);
    }
    __syncthreads();
#pragma unroll 4
    for (int k = 0; k < 32; ++k) {
      float4 b1 = *reinterpret_cast<const float4*>(&Ws1[k][tc * 4]);
      float4 b2 = *reinterpret_cast<const float4*>(&Ws2[k][tc * 4]);
      float4 bm = *reinterpret_cast<const float4*>(&Wsm[k][tc * 4]);
#pragma unroll
      for (int i = 0; i < 2; ++i) {
        float ar = Asr[tr * 2 + i][k], ai = Asi[tr * 2 + i][k];
        a1r[i][0] += ar * b1.x; a1r[i][1] += ar * b1.y; a1r[i][2] += ar * b1.z; a1r[i][3] += ar * b1.w;
        a1i[i][0] += ai * b1.x; a1i[i][1] += ai * b1.y; a1i[i][2] += ai * b1.z; a1i[i][3] += ai * b1.w;
        a2r[i][0] += ar * b2.x; a2r[i][1] += ar * b2.y; a2r[i][2] += ar * b2.z; a2r[i][3] += ar * b2.w;
        a2i[i][0] += ai * b2.x; a2i[i][1] += ai * b2.y; a2i[i][2] += ai * b2.z; a2i[i][3] += ai * b2.w;
        amr[i][0] += ar * bm.x; amr[i][1] += ar * bm.y; amr[i][2] += ar * bm.z; amr[i][3] += ar * bm.w;
        ami[i][0] += ai * bm.x; ami[i][1] += ai * bm.y; ami[i][2] += ai * bm.z; ami[i][3] += ai * bm.w;
      }
    }
    __syncthreads();
  }
  float b0 = bias[tc * 4 + 0], bb1 = bias[tc * 4 + 1];
  float b2v = bias[tc * 4 + 2], b3 = bias[tc * 4 + 3];
#pragma unroll
  for (int i = 0; i < 2; ++i) {
    int gr = r0 + tr * 2 + i;
    if (gr >= M) continue;
    size_t pb = (size_t)gr * 128 + tc * 8;
    *reinterpret_cast<float4*>(&P1[pb]) =
        make_float4(a1r[i][0], a1i[i][0], a1r[i][1], a1i[i][1]);
    *reinterpret_cast<float4*>(&P1[pb + 4]) =
        make_float4(a1r[i][2], a1i[i][2], a1r[i][3], a1i[i][3]);
    *reinterpret_cast<float4*>(&P2[pb]) =
        make_float4(a2r[i][0], a2i[i][0], a2r[i][1], a2i[i][1]);
    *reinterpret_cast<float4*>(&P2[pb + 4]) =
        make_float4(a2r[i][2], a2i[i][2], a2r[i][3], a2i[i][3]);
    size_t hb = (size_t)gr * 64 + tc * 4;
    *reinterpret_cast<float4*>(&Hr[hb]) =
        make_float4(amr[i][0] - ami[i][0] + b0, amr[i][1] - ami[i][1] + bb1,
                    amr[i][2] - ami[i][2] + b2v, amr[i][3] - ami[i][3] + b3);
    *reinterpret_cast<float4*>(&Hi[hb]) =
        make_float4(amr[i][0] + ami[i][0] + b0, amr[i][1] + ami[i][1] + bb1,
                    amr[i][2] + ami[i][2] + b2v, amr[i][3] + ami[i][3] + b3);
  }
}

// ---- exclusive scan of cnt (= dc>>32) -> rp ---------------------------------
__global__ __launch_bounds__(256) void k_scan1(
    const unsigned long long* __restrict__ dc, int* __restrict__ rp,
    int* __restrict__ bsum, int N) {
  __shared__ int sh[256];
  int t = threadIdx.x;
  int base = blockIdx.x * 1024 + t * 4;
  int c0 = (base + 0 < N) ? (int)(dc[base + 0] >> 32) : 0;
  int c1 = (base + 1 < N) ? (int)(dc[base + 1] >> 32) : 0;
  int c2 = (base + 2 < N) ? (int)(dc[base + 2] >> 32) : 0;
  int c3 = (base + 3 < N) ? (int)(dc[base + 3] >> 32) : 0;
  int s = c0 + c1 + c2 + c3;
  sh[t] = s;
  __syncthreads();
  for (int o = 1; o < 256; o <<= 1) {
    int y = (t >= o) ? sh[t - o] : 0;
    __syncthreads();
    if (t >= o) sh[t] += y;
    __syncthreads();
  }
  int excl = sh[t] - s;
  if (base + 0 < N) rp[base + 0] = excl;
  if (base + 1 < N) rp[base + 1] = excl + c0;
  if (base + 2 < N) rp[base + 2] = excl + c0 + c1;
  if (base + 3 < N) rp[base + 3] = excl + c0 + c1 + c2;
  if (t == 255) bsum[blockIdx.x] = sh[255];
}

// ---- scan3 with folded block-sum prefix (kills the scan2 launch) ------------
__global__ void k_scan3(int* __restrict__ rp, int* __restrict__ nxt,
                        const int* __restrict__ bsum, int N, int twoE) {
  int i = blockIdx.x * 256 + threadIdx.x;
  if (i > N) return;
  if (i == N) { rp[N] = twoE; return; }
  int b = i >> 10;
  int pre = 0;
  for (int j = 0; j < b; ++j) pre += bsum[j];  // <=48 iters, wave-uniform
  int val = rp[i] + pre;
  rp[i] = val;
  nxt[i] = val;
}

// ---- scatter edge records: src[pos], cf[pos]=(cr,ci) ------------------------
__global__ void k_scatter(const int* __restrict__ u, const int* __restrict__ v,
                          const float* __restrict__ w,
                          const unsigned long long* __restrict__ dc,
                          int* __restrict__ nxt, int* __restrict__ src,
                          float2* __restrict__ cf, int E) {
  int e = blockIdx.x * 256 + threadIdx.x;
  if (e >= E) return;
  int a = u[e], b = v[e];
  float we = w[e];
  float da = (float)(unsigned)dc[a] * (1.f / 16777216.f);
  float db = (float)(unsigned)dc[b] * (1.f / 16777216.f);
  float ia = da > 0.f ? rsqrtf(da) : 0.f;
  float ib = db > 0.f ? rsqrtf(db) : 0.f;
  float norm = ia * (0.5f * we) * ib;
  float th = 1.57079632679489662f * we;  // 2*pi*q*w, q=0.25
  float sn, cs;
  sincosf(th, &sn, &cs);
  float cr = -norm * cs, ci = -norm * sn;
  int p1 = atomicAdd(&nxt[b], 1);  // forward a->b, coeff (cr, ci)
  src[p1] = a;
  cf[p1] = make_float2(cr, ci);
  int p2 = atomicAdd(&nxt[a], 1);  // reverse b->a, coeff (cr, -ci)
  src[p2] = b;
  cf[p2] = make_float2(cr, -ci);
}

// ---- gU: u-streams of prop(g2) + fused comb: Z = [P1+2*(u0,u1) | P1+2*(u2,u3)]
__global__ __launch_bounds__(256) void k_gU(
    const int* __restrict__ src, const float2* __restrict__ cf,
    const int* __restrict__ rp, const float* __restrict__ P2,
    const float* __restrict__ P1, float* __restrict__ Z, int N) {
  int d = blockIdx.x * 4 + (threadIdx.x >> 6);
  if (d >= N) return;
  int lane = threadIdx.x & 63;
  int g = lane >> 5, lg = lane & 31;
  float4 a01 = {0, 0, 0, 0};
  float4 a23 = {0, 0, 0, 0};
  int k1 = rp[d + 1];
#pragma unroll 2
  for (int k = rp[d] + g; k < k1; k += 2) {
    int s = src[k];
    float2 c = cf[k];
    float4 v = ld4(P2 + (size_t)s * 128 + lg * 4);
    a01.x += c.x * v.x; a01.y += c.y * v.y;
    a01.z += c.x * v.z; a01.w += c.y * v.w;
    a23.x += c.y * v.x; a23.y += c.x * v.y;
    a23.z += c.y * v.z; a23.w += c.x * v.w;
  }
  a01.x += __shfl_xor(a01.x, 32); a01.y += __shfl_xor(a01.y, 32);
  a01.z += __shfl_xor(a01.z, 32); a01.w += __shfl_xor(a01.w, 32);
  a23.x += __shfl_xor(a23.x, 32); a23.y += __shfl_xor(a23.y, 32);
  a23.z += __shfl_xor(a23.z, 32); a23.w += __shfl_xor(a23.w, 32);
  float4 p = ld4(P1 + (size_t)d * 128 + lg * 4);
  size_t zb = (size_t)d * 256 + lg * 4;
  if (g == 0)
    *reinterpret_cast<float4*>(&Z[zb]) =
        make_float4(p.x + 2.f * a01.x, p.y + 2.f * a01.y,
                    p.z + 2.f * a01.z, p.w + 2.f * a01.w);
  else
    *reinterpret_cast<float4*>(&Z[zb + 128]) =
        make_float4(p.x + 2.f * a23.x, p.y + 2.f * a23.y,
                    p.z + 2.f * a23.z, p.w + 2.f * a23.w);
}

// ---- gC: hr += cr*z1r - ci*z1i; hi += ci*z2r + cr*z2i; complex ReLU ---------
__global__ __launch_bounds__(256) void k_gC(
    const int* __restrict__ src, const float2* __restrict__ cf,
    const int* __restrict__ rp, const float* __restrict__ Z,
    float* __restrict__ Hr, float* __restrict__ Hi, int N) {
  int d = blockIdx.x * 4 + (threadIdx.x >> 6);
  if (d >= N) return;
  int lane = threadIdx.x & 63;
  int g = lane >> 5, lg = lane & 31;
  float2 ahr = {0, 0}, ahi = {0, 0};
  int k1 = rp[d + 1];
#pragma unroll 2
  for (int k = rp[d] + g; k < k1; k += 2) {
    int s = src[k];
    float2 c = cf[k];
    const float* row = Z + (size_t)s * 256 + lg * 4;
    float4 z1 = ld4(row);
    float4 z2 = ld4(row + 128);
    ahr.x += c.x * z1.x - c.y * z1.y;
    ahr.y += c.x * z1.z - c.y * z1.w;
    ahi.x += c.y * z2.x + c.x * z2.y;
    ahi.y += c.y * z2.z + c.x * z2.w;
  }
  ahr.x += __shfl_xor(ahr.x, 32);
  ahr.y += __shfl_xor(ahr.y, 32);
  ahi.x += __shfl_xor(ahi.x, 32);
  ahi.y += __shfl_xor(ahi.y, 32);
  if (g == 0) {
    size_t hb = (size_t)d * 64 + lg * 2;
    float2 hr = ld2(&Hr[hb]);
    float2 hi = ld2(&Hi[hb]);
    hr.x += ahr.x; hr.y += ahr.y;
    hi.x += ahi.x; hi.y += ahi.y;
    if (hr.x < 0.f) { hr.x = 0.f; hi.x = 0.f; }
    if (hr.y < 0.f) { hr.y = 0.f; hi.y = 0.f; }
    *reinterpret_cast<float2*>(&Hr[hb]) = hr;
    *reinterpret_cast<float2*>(&Hi[hb]) = hi;
  }
}

// ---- query gather + linear + log_softmax ------------------------------------
__global__ __launch_bounds__(256) void k_query(
    const int* __restrict__ qe, const float* __restrict__ xr,
    const float* __restrict__ xi, const float* __restrict__ Wlin,
    const float* __restrict__ blin, float* __restrict__ out, int Q) {
  int q = blockIdx.x * 4 + (threadIdx.x >> 6);
  if (q >= Q) return;
  int lane = threadIdx.x & 63;
  int q0 = qe[2 * q], q1 = qe[2 * q + 1];
  float x0 = xr[(size_t)q0 * 64 + lane];
  float x1 = xr[(size_t)q1 * 64 + lane];
  float x2 = xi[(size_t)q0 * 64 + lane];
  float x3 = xi[(size_t)q1 * 64 + lane];
  float l0 = x0 * Wlin[lane] + x1 * Wlin[64 + lane] + x2 * Wlin[128 + lane] + x3 * Wlin[192 + lane];
  float l1 = x0 * Wlin[256 + lane] + x1 * Wlin[320 + lane] + x2 * Wlin[384 + lane] + x3 * Wlin[448 + lane];
#pragma unroll
  for (int o = 32; o > 0; o >>= 1) {
    l0 += __shfl_xor(l0, o);
    l1 += __shfl_xor(l1, o);
  }
  if (lane == 0) {
    l0 += blin[0];
    l1 += blin[1];
    float m = fmaxf(l0, l1);
    float lse = m + logf(expf(l0 - m) + expf(l1 - m));
    out[2 * q + 0] = l0 - lse;
    out[2 * q + 1] = l1 - lse;
  }
}

extern "C" void kernel_launch(void* const* d_in, const int* in_sizes, int n_in,
                              void* d_out, int out_size, void* d_ws, size_t ws_size,
                              hipStream_t stream) {
  const float* real = (const float*)d_in[0];
  const float* imag = (const float*)d_in[1];
  const int* ei     = (const int*)d_in[2];
  const int* qe     = (const int*)d_in[3];
  const float* ew   = (const float*)d_in[4];
  const float* W1   = (const float*)d_in[5];
  const float* b1   = (const float*)d_in[6];
  const float* W2   = (const float*)d_in[7];
  const float* b2   = (const float*)d_in[8];
  const float* Wlin = (const float*)d_in[9];
  const float* blin = (const float*)d_in[10];

  const int N = in_sizes[0] / 128;
  const int E = in_sizes[4];
  const int Q = in_sizes[3] / 2;
  const int* u = ei;
  const int* v = ei + E;

  float* ws = (float*)d_ws;
  size_t off = 0;
  auto alloc = [&](size_t n) { float* p = ws + off; off += n; return p; };
  const size_t N64 = (size_t)N * 64;
  const size_t N128 = (size_t)N * 128;
  const size_t N256 = (size_t)N * 256;

  float2* cf = (float2*)alloc((size_t)2 * E * 2);                 // 8B-aligned
  unsigned long long* dc = (unsigned long long*)alloc((size_t)2 * N);
  int* src  = (int*)alloc((size_t)2 * E);
  float* P1  = alloc(N128);
  float* P2  = alloc(N128);
  float* Z   = alloc(N256);
  float* HAr = alloc(N64);
  float* HAi = alloc(N64);
  float* HBr = alloc(N64);
  float* HBi = alloc(N64);
  int* rp   = (int*)alloc(N + 1);
  int* nxt  = (int*)alloc(N);
  int* bsum = (int*)alloc(64);
  (void)ws_size; (void)n_in; (void)out_size;

  const int eb = (E + 255) / 256;
  const int mb = (N + 31) / 32;
  const int NB = (N + 1023) / 1024;
  const int gb = (N + 3) / 4;

  // --- dispatch 1: deg_count || layer-1 GEMM (independent block ranges) ---
  hipMemsetAsync(dc, 0, (size_t)N * 8, stream);
  k_fuse_deg_gemm<128><<<eb + mb, 256, 0, stream>>>(
      u, v, ew, dc, E, eb, real, imag, W1, b1, P1, P2, HAr, HAi, N);
  // --- graph structure ---
  k_scan1<<<NB, 256, 0, stream>>>(dc, rp, bsum, N);
  k_scan3<<<(N + 256) / 256, 256, 0, stream>>>(rp, nxt, bsum, N, 2 * E);
  k_scatter<<<eb, 256, 0, stream>>>(u, v, ew, dc, nxt, src, cf, E);

  // --- layer 1 sparse ---
  k_gU<<<gb, 256, 0, stream>>>(src, cf, rp, P2, P1, Z, N);
  k_gC<<<gb, 256, 0, stream>>>(src, cf, rp, Z, HAr, HAi, N);

  // --- layer 2 ---
  k_gemmF<64><<<mb, 256, 0, stream>>>(HAr, HAi, W2, b2, P1, P2, HBr, HBi, N);
  k_gU<<<gb, 256, 0, stream>>>(src, cf, rp, P2, P1, Z, N);
  k_gC<<<gb, 256, 0, stream>>>(src, cf, rp, Z, HBr, HBi, N);

  // --- queries ---
  k_query<<<(Q + 3) / 4, 256, 0, stream>>>(qe, HBr, HBi, Wlin, blin, (float*)d_out, Q);
}

// Round 11
// 670.330 us; speedup vs baseline: 1.0292x; 1.0292x over previous
//
#include <hip/hip_runtime.h>

// ---------------------------------------------------------------------------
// MagNet link prediction forward, f32 (16-bit quant of propagated streams
// fails: complex-ReLU mask flips amplify tiny hr errors — rounds 3/4).
// Gather (CSR), telescoped Chebyshev: out = x@(W0-W2)+b + prop(g1+2*prop(g2)).
// Round 11: deg_count FUSED as a fire-and-forget edge-slice PREFIX inside
// every layer-1 GEMM block (round 10's block-partition fusion failed: deg
// blocks inherited 33.8KB LDS and serialized). Each of the mb GEMM blocks
// issues ~320 edges' packed atomics (no return value -> no waitcnt) before
// staging its A tile; atomic latency hides under the block's GEMM VALU work.
// Sparse passes unchanged: pinned at the ~3.65 TB/s random-gather L2-fill
// wall (invariant across 5 structures, rounds 2..9; bytes at algebraic min).
// ---------------------------------------------------------------------------

__device__ __forceinline__ float4 ld4(const float* __restrict__ p) {
  return *reinterpret_cast<const float4*>(p);
}
__device__ __forceinline__ float2 ld2(const float* __restrict__ p) {
  return *reinterpret_cast<const float2*>(p);
}

// ---- fused: [edge-slice deg atomics prefix] + 6-stream GEMM (layer 1) -------
template <int K>
__global__ __launch_bounds__(256) void k_gemm_deg(
    const int* __restrict__ u, const int* __restrict__ v,
    const float* __restrict__ w, unsigned long long* __restrict__ dc, int E,
    int epb,
    const float* __restrict__ Ar, const float* __restrict__ Ai,
    const float* __restrict__ W,  // [3][K][64]
    const float* __restrict__ bias,
    float* __restrict__ P1, float* __restrict__ P2,
    float* __restrict__ Hr, float* __restrict__ Hi, int M) {
  __shared__ float Asr[32][36];
  __shared__ float Asi[32][36];
  __shared__ float Ws1[32][64];
  __shared__ float Ws2[32][64];
  __shared__ float Wsm[32][64];
  const int t = threadIdx.x;
  {  // --- deg prefix: fire-and-forget packed atomics, no dependent reads ---
    int e0 = blockIdx.x * epb;
    int e1 = min(e0 + epb, E);
    for (int e = e0 + t; e < e1; e += 256) {
      float hw = 0.5f * w[e];
      unsigned fx = __float2uint_rn(hw * 16777216.f);  // 2^24 fixed point
      unsigned long long pk = (1ULL << 32) | (unsigned long long)fx;
      atomicAdd(&dc[u[e]], pk);
      atomicAdd(&dc[v[e]], pk);
    }
  }
  // --- GEMM: BM=32, BK=32, A+W in LDS ---
  const int r0 = blockIdx.x * 32;
  const int tc = t & 15, tr = t >> 4;
  const float* W0 = W;
  const float* W1 = W + (size_t)K * 64;
  const float* W2 = W + (size_t)2 * K * 64;
  float a1r[2][4] = {}, a1i[2][4] = {}, a2r[2][4] = {}, a2i[2][4] = {};
  float amr[2][4] = {}, ami[2][4] = {};
  for (int k0 = 0; k0 < K; k0 += 32) {
    {  // A tile: 32 rows x 8 float4, one per thread per array
      int row = t >> 3, c4 = t & 7;
      int gr = r0 + row;
      float4 fr = make_float4(0.f, 0.f, 0.f, 0.f), fi = fr;
      if (gr < M) {
        fr = ld4(&Ar[(size_t)gr * K + k0 + c4 * 4]);
        fi = ld4(&Ai[(size_t)gr * K + k0 + c4 * 4]);
      }
      *reinterpret_cast<float4*>(&Asr[row][c4 * 4]) = fr;
      *reinterpret_cast<float4*>(&Asi[row][c4 * 4]) = fi;
    }
    for (int li = t; li < 512; li += 256) {  // W tiles: 32 rows x 16 f4 each
      int row = li >> 4, c4 = li & 15;
      size_t woff = (size_t)(k0 + row) * 64 + c4 * 4;
      float4 w1 = ld4(&W1[woff]);
      float4 w2 = ld4(&W2[woff]);
      float4 w0 = ld4(&W0[woff]);
      *reinterpret_cast<float4*>(&Ws1[row][c4 * 4]) = w1;
      *reinterpret_cast<float4*>(&Ws2[row][c4 * 4]) = w2;
      *reinterpret_cast<float4*>(&Wsm[row][c4 * 4]) =
          make_float4(w0.x - w2.x, w0.y - w2.y, w0.z - w2.z, w0.w - w2.w);
    }
    __syncthreads();
#pragma unroll 4
    for (int k = 0; k < 32; ++k) {
      float4 b1 = *reinterpret_cast<const float4*>(&Ws1[k][tc * 4]);
      float4 b2 = *reinterpret_cast<const float4*>(&Ws2[k][tc * 4]);
      float4 bm = *reinterpret_cast<const float4*>(&Wsm[k][tc * 4]);
#pragma unroll
      for (int i = 0; i < 2; ++i) {
        float ar = Asr[tr * 2 + i][k], ai = Asi[tr * 2 + i][k];
        a1r[i][0] += ar * b1.x; a1r[i][1] += ar * b1.y; a1r[i][2] += ar * b1.z; a1r[i][3] += ar * b1.w;
        a1i[i][0] += ai * b1.x; a1i[i][1] += ai * b1.y; a1i[i][2] += ai * b1.z; a1i[i][3] += ai * b1.w;
        a2r[i][0] += ar * b2.x; a2r[i][1] += ar * b2.y; a2r[i][2] += ar * b2.z; a2r[i][3] += ar * b2.w;
        a2i[i][0] += ai * b2.x; a2i[i][1] += ai * b2.y; a2i[i][2] += ai * b2.z; a2i[i][3] += ai * b2.w;
        amr[i][0] += ar * bm.x; amr[i][1] += ar * bm.y; amr[i][2] += ar * bm.z; amr[i][3] += ar * bm.w;
        ami[i][0] += ai * bm.x; ami[i][1] += ai * bm.y; ami[i][2] += ai * bm.z; ami[i][3] += ai * bm.w;
      }
    }
    __syncthreads();
  }
  float b0 = bias[tc * 4 + 0], bb1 = bias[tc * 4 + 1];
  float b2v = bias[tc * 4 + 2], b3 = bias[tc * 4 + 3];
#pragma unroll
  for (int i = 0; i < 2; ++i) {
    int gr = r0 + tr * 2 + i;
    if (gr >= M) continue;
    size_t pb = (size_t)gr * 128 + tc * 8;  // feature pairs f=4tc..4tc+3
    *reinterpret_cast<float4*>(&P1[pb]) =
        make_float4(a1r[i][0], a1i[i][0], a1r[i][1], a1i[i][1]);
    *reinterpret_cast<float4*>(&P1[pb + 4]) =
        make_float4(a1r[i][2], a1i[i][2], a1r[i][3], a1i[i][3]);
    *reinterpret_cast<float4*>(&P2[pb]) =
        make_float4(a2r[i][0], a2i[i][0], a2r[i][1], a2i[i][1]);
    *reinterpret_cast<float4*>(&P2[pb + 4]) =
        make_float4(a2r[i][2], a2i[i][2], a2r[i][3], a2i[i][3]);
    size_t hb = (size_t)gr * 64 + tc * 4;
    *reinterpret_cast<float4*>(&Hr[hb]) =
        make_float4(amr[i][0] - ami[i][0] + b0, amr[i][1] - ami[i][1] + bb1,
                    amr[i][2] - ami[i][2] + b2v, amr[i][3] - ami[i][3] + b3);
    *reinterpret_cast<float4*>(&Hi[hb]) =
        make_float4(amr[i][0] + ami[i][0] + b0, amr[i][1] + ami[i][1] + bb1,
                    amr[i][2] + ami[i][2] + b2v, amr[i][3] + ami[i][3] + b3);
  }
}

// ---- standalone GEMM (layer 2) ----------------------------------------------
template <int K>
__global__ __launch_bounds__(256) void k_gemmF(
    const float* __restrict__ Ar, const float* __restrict__ Ai,
    const float* __restrict__ W, const float* __restrict__ bias,
    float* __restrict__ P1, float* __restrict__ P2,
    float* __restrict__ Hr, float* __restrict__ Hi, int M) {
  __shared__ float Asr[32][36];
  __shared__ float Asi[32][36];
  __shared__ float Ws1[32][64];
  __shared__ float Ws2[32][64];
  __shared__ float Wsm[32][64];
  const int t = threadIdx.x;
  const int r0 = blockIdx.x * 32;
  const int tc = t & 15, tr = t >> 4;
  const float* W0 = W;
  const float* W1 = W + (size_t)K * 64;
  const float* W2 = W + (size_t)2 * K * 64;
  float a1r[2][4] = {}, a1i[2][4] = {}, a2r[2][4] = {}, a2i[2][4] = {};
  float amr[2][4] = {}, ami[2][4] = {};
  for (int k0 = 0; k0 < K; k0 += 32) {
    {
      int row = t >> 3, c4 = t & 7;
      int gr = r0 + row;
      float4 fr = make_float4(0.f, 0.f, 0.f, 0.f), fi = fr;
      if (gr < M) {
        fr = ld4(&Ar[(size_t)gr * K + k0 + c4 * 4]);
        fi = ld4(&Ai[(size_t)gr * K + k0 + c4 * 4]);
      }
      *reinterpret_cast<float4*>(&Asr[row][c4 * 4]) = fr;
      *reinterpret_cast<float4*>(&Asi[row][c4 * 4]) = fi;
    }
    for (int li = t; li < 512; li += 256) {
      int row = li >> 4, c4 = li & 15;
      size_t woff = (size_t)(k0 + row) * 64 + c4 * 4;
      float4 w1 = ld4(&W1[woff]);
      float4 w2 = ld4(&W2[woff]);
      float4 w0 = ld4(&W0[woff]);
      *reinterpret_cast<float4*>(&Ws1[row][c4 * 4]) = w1;
      *reinterpret_cast<float4*>(&Ws2[row][c4 * 4]) = w2;
      *reinterpret_cast<float4*>(&Wsm[row][c4 * 4]) =
          make_float4(w0.x - w2.x, w0.y - w2.y, w0.z - w2.z, w0.w - w2.w);
    }
    __syncthreads();
#pragma unroll 4
    for (int k = 0; k < 32; ++k) {
      float4 b1 = *reinterpret_cast<const float4*>(&Ws1[k][tc * 4]);
      float4 b2 = *reinterpret_cast<const float4*>(&Ws2[k][tc * 4]);
      float4 bm = *reinterpret_cast<const float4*>(&Wsm[k][tc * 4]);
#pragma unroll
      for (int i = 0; i < 2; ++i) {
        float ar = Asr[tr * 2 + i][k], ai = Asi[tr * 2 + i][k];
        a1r[i][0] += ar * b1.x; a1r[i][1] += ar * b1.y; a1r[i][2] += ar * b1.z; a1r[i][3] += ar * b1.w;
        a1i[i][0] += ai * b1.x; a1i[i][1] += ai * b1.y; a1i[i][2] += ai * b1.z; a1i[i][3] += ai * b1.w;
        a2r[i][0] += ar * b2.x; a2r[i][1] += ar * b2.y; a2r[i][2] += ar * b2.z; a2r[i][3] += ar * b2.w;
        a2i[i][0] += ai * b2.x; a2i[i][1] += ai * b2.y; a2i[i][2] += ai * b2.z; a2i[i][3] += ai * b2.w;
        amr[i][0] += ar * bm.x; amr[i][1] += ar * bm.y; amr[i][2] += ar * bm.z; amr[i][3] += ar * bm.w;
        ami[i][0] += ai * bm.x; ami[i][1] += ai * bm.y; ami[i][2] += ai * bm.z; ami[i][3] += ai * bm.w;
      }
    }
    __syncthreads();
  }
  float b0 = bias[tc * 4 + 0], bb1 = bias[tc * 4 + 1];
  float b2v = bias[tc * 4 + 2], b3 = bias[tc * 4 + 3];
#pragma unroll
  for (int i = 0; i < 2; ++i) {
    int gr = r0 + tr * 2 + i;
    if (gr >= M) continue;
    size_t pb = (size_t)gr * 128 + tc * 8;
    *reinterpret_cast<float4*>(&P1[pb]) =
        make_float4(a1r[i][0], a1i[i][0], a1r[i][1], a1i[i][1]);
    *reinterpret_cast<float4*>(&P1[pb + 4]) =
        make_float4(a1r[i][2], a1i[i][2], a1r[i][3], a1i[i][3]);
    *reinterpret_cast<float4*>(&P2[pb]) =
        make_float4(a2r[i][0], a2i[i][0], a2r[i][1], a2i[i][1]);
    *reinterpret_cast<float4*>(&P2[pb + 4]) =
        make_float4(a2r[i][2], a2i[i][2], a2r[i][3], a2i[i][3]);
    size_t hb = (size_t)gr * 64 + tc * 4;
    *reinterpret_cast<float4*>(&Hr[hb]) =
        make_float4(amr[i][0] - ami[i][0] + b0, amr[i][1] - ami[i][1] + bb1,
                    amr[i][2] - ami[i][2] + b2v, amr[i][3] - ami[i][3] + b3);
    *reinterpret_cast<float4*>(&Hi[hb]) =
        make_float4(amr[i][0] + ami[i][0] + b0, amr[i][1] + ami[i][1] + bb1,
                    amr[i][2] + ami[i][2] + b2v, amr[i][3] + ami[i][3] + b3);
  }
}

// ---- exclusive scan of cnt (= dc>>32) -> rp ---------------------------------
__global__ __launch_bounds__(256) void k_scan1(
    const unsigned long long* __restrict__ dc, int* __restrict__ rp,
    int* __restrict__ bsum, int N) {
  __shared__ int sh[256];
  int t = threadIdx.x;
  int base = blockIdx.x * 1024 + t * 4;
  int c0 = (base + 0 < N) ? (int)(dc[base + 0] >> 32) : 0;
  int c1 = (base + 1 < N) ? (int)(dc[base + 1] >> 32) : 0;
  int c2 = (base + 2 < N) ? (int)(dc[base + 2] >> 32) : 0;
  int c3 = (base + 3 < N) ? (int)(dc[base + 3] >> 32) : 0;
  int s = c0 + c1 + c2 + c3;
  sh[t] = s;
  __syncthreads();
  for (int o = 1; o < 256; o <<= 1) {
    int y = (t >= o) ? sh[t - o] : 0;
    __syncthreads();
    if (t >= o) sh[t] += y;
    __syncthreads();
  }
  int excl = sh[t] - s;
  if (base + 0 < N) rp[base + 0] = excl;
  if (base + 1 < N) rp[base + 1] = excl + c0;
  if (base + 2 < N) rp[base + 2] = excl + c0 + c1;
  if (base + 3 < N) rp[base + 3] = excl + c0 + c1 + c2;
  if (t == 255) bsum[blockIdx.x] = sh[255];
}

// ---- scan3 with folded block-sum prefix -------------------------------------
__global__ void k_scan3(int* __restrict__ rp, int* __restrict__ nxt,
                        const int* __restrict__ bsum, int N, int twoE) {
  int i = blockIdx.x * 256 + threadIdx.x;
  if (i > N) return;
  if (i == N) { rp[N] = twoE; return; }
  int b = i >> 10;
  int pre = 0;
  for (int j = 0; j < b; ++j) pre += bsum[j];  // <=48 iters, wave-uniform
  int val = rp[i] + pre;
  rp[i] = val;
  nxt[i] = val;
}

// ---- scatter edge records: src[pos], cf[pos]=(cr,ci) ------------------------
__global__ void k_scatter(const int* __restrict__ u, const int* __restrict__ v,
                          const float* __restrict__ w,
                          const unsigned long long* __restrict__ dc,
                          int* __restrict__ nxt, int* __restrict__ src,
                          float2* __restrict__ cf, int E) {
  int e = blockIdx.x * 256 + threadIdx.x;
  if (e >= E) return;
  int a = u[e], b = v[e];
  float we = w[e];
  float da = (float)(unsigned)dc[a] * (1.f / 16777216.f);
  float db = (float)(unsigned)dc[b] * (1.f / 16777216.f);
  float ia = da > 0.f ? rsqrtf(da) : 0.f;
  float ib = db > 0.f ? rsqrtf(db) : 0.f;
  float norm = ia * (0.5f * we) * ib;
  float th = 1.57079632679489662f * we;  // 2*pi*q*w, q=0.25
  float sn, cs;
  sincosf(th, &sn, &cs);
  float cr = -norm * cs, ci = -norm * sn;
  int p1 = atomicAdd(&nxt[b], 1);  // forward a->b, coeff (cr, ci)
  src[p1] = a;
  cf[p1] = make_float2(cr, ci);
  int p2 = atomicAdd(&nxt[a], 1);  // reverse b->a, coeff (cr, -ci)
  src[p2] = b;
  cf[p2] = make_float2(cr, -ci);
}

// ---- gU: u-streams of prop(g2) + fused comb: Z = [P1+2*(u0,u1) | P1+2*(u2,u3)]
__global__ __launch_bounds__(256) void k_gU(
    const int* __restrict__ src, const float2* __restrict__ cf,
    const int* __restrict__ rp, const float* __restrict__ P2,
    const float* __restrict__ P1, float* __restrict__ Z, int N) {
  int d = blockIdx.x * 4 + (threadIdx.x >> 6);
  if (d >= N) return;
  int lane = threadIdx.x & 63;
  int g = lane >> 5, lg = lane & 31;
  float4 a01 = {0, 0, 0, 0};
  float4 a23 = {0, 0, 0, 0};
  int k1 = rp[d + 1];
#pragma unroll 2
  for (int k = rp[d] + g; k < k1; k += 2) {
    int s = src[k];
    float2 c = cf[k];
    float4 v = ld4(P2 + (size_t)s * 128 + lg * 4);
    a01.x += c.x * v.x; a01.y += c.y * v.y;
    a01.z += c.x * v.z; a01.w += c.y * v.w;
    a23.x += c.y * v.x; a23.y += c.x * v.y;
    a23.z += c.y * v.z; a23.w += c.x * v.w;
  }
  a01.x += __shfl_xor(a01.x, 32); a01.y += __shfl_xor(a01.y, 32);
  a01.z += __shfl_xor(a01.z, 32); a01.w += __shfl_xor(a01.w, 32);
  a23.x += __shfl_xor(a23.x, 32); a23.y += __shfl_xor(a23.y, 32);
  a23.z += __shfl_xor(a23.z, 32); a23.w += __shfl_xor(a23.w, 32);
  float4 p = ld4(P1 + (size_t)d * 128 + lg * 4);
  size_t zb = (size_t)d * 256 + lg * 4;
  if (g == 0)
    *reinterpret_cast<float4*>(&Z[zb]) =
        make_float4(p.x + 2.f * a01.x, p.y + 2.f * a01.y,
                    p.z + 2.f * a01.z, p.w + 2.f * a01.w);
  else
    *reinterpret_cast<float4*>(&Z[zb + 128]) =
        make_float4(p.x + 2.f * a23.x, p.y + 2.f * a23.y,
                    p.z + 2.f * a23.z, p.w + 2.f * a23.w);
}

// ---- gC: hr += cr*z1r - ci*z1i; hi += ci*z2r + cr*z2i; complex ReLU ---------
__global__ __launch_bounds__(256) void k_gC(
    const int* __restrict__ src, const float2* __restrict__ cf,
    const int* __restrict__ rp, const float* __restrict__ Z,
    float* __restrict__ Hr, float* __restrict__ Hi, int N) {
  int d = blockIdx.x * 4 + (threadIdx.x >> 6);
  if (d >= N) return;
  int lane = threadIdx.x & 63;
  int g = lane >> 5, lg = lane & 31;
  float2 ahr = {0, 0}, ahi = {0, 0};
  int k1 = rp[d + 1];
#pragma unroll 2
  for (int k = rp[d] + g; k < k1; k += 2) {
    int s = src[k];
    float2 c = cf[k];
    const float* row = Z + (size_t)s * 256 + lg * 4;
    float4 z1 = ld4(row);
    float4 z2 = ld4(row + 128);
    ahr.x += c.x * z1.x - c.y * z1.y;
    ahr.y += c.x * z1.z - c.y * z1.w;
    ahi.x += c.y * z2.x + c.x * z2.y;
    ahi.y += c.y * z2.z + c.x * z2.w;
  }
  ahr.x += __shfl_xor(ahr.x, 32);
  ahr.y += __shfl_xor(ahr.y, 32);
  ahi.x += __shfl_xor(ahi.x, 32);
  ahi.y += __shfl_xor(ahi.y, 32);
  if (g == 0) {
    size_t hb = (size_t)d * 64 + lg * 2;
    float2 hr = ld2(&Hr[hb]);
    float2 hi = ld2(&Hi[hb]);
    hr.x += ahr.x; hr.y += ahr.y;
    hi.x += ahi.x; hi.y += ahi.y;
    if (hr.x < 0.f) { hr.x = 0.f; hi.x = 0.f; }
    if (hr.y < 0.f) { hr.y = 0.f; hi.y = 0.f; }
    *reinterpret_cast<float2*>(&Hr[hb]) = hr;
    *reinterpret_cast<float2*>(&Hi[hb]) = hi;
  }
}

// ---- query gather + linear + log_softmax ------------------------------------
__global__ __launch_bounds__(256) void k_query(
    const int* __restrict__ qe, const float* __restrict__ xr,
    const float* __restrict__ xi, const float* __restrict__ Wlin,
    const float* __restrict__ blin, float* __restrict__ out, int Q) {
  int q = blockIdx.x * 4 + (threadIdx.x >> 6);
  if (q >= Q) return;
  int lane = threadIdx.x & 63;
  int q0 = qe[2 * q], q1 = qe[2 * q + 1];
  float x0 = xr[(size_t)q0 * 64 + lane];
  float x1 = xr[(size_t)q1 * 64 + lane];
  float x2 = xi[(size_t)q0 * 64 + lane];
  float x3 = xi[(size_t)q1 * 64 + lane];
  float l0 = x0 * Wlin[lane] + x1 * Wlin[64 + lane] + x2 * Wlin[128 + lane] + x3 * Wlin[192 + lane];
  float l1 = x0 * Wlin[256 + lane] + x1 * Wlin[320 + lane] + x2 * Wlin[384 + lane] + x3 * Wlin[448 + lane];
#pragma unroll
  for (int o = 32; o > 0; o >>= 1) {
    l0 += __shfl_xor(l0, o);
    l1 += __shfl_xor(l1, o);
  }
  if (lane == 0) {
    l0 += blin[0];
    l1 += blin[1];
    float m = fmaxf(l0, l1);
    float lse = m + logf(expf(l0 - m) + expf(l1 - m));
    out[2 * q + 0] = l0 - lse;
    out[2 * q + 1] = l1 - lse;
  }
}

extern "C" void kernel_launch(void* const* d_in, const int* in_sizes, int n_in,
                              void* d_out, int out_size, void* d_ws, size_t ws_size,
                              hipStream_t stream) {
  const float* real = (const float*)d_in[0];
  const float* imag = (const float*)d_in[1];
  const int* ei     = (const int*)d_in[2];
  const int* qe     = (const int*)d_in[3];
  const float* ew   = (const float*)d_in[4];
  const float* W1   = (const float*)d_in[5];
  const float* b1   = (const float*)d_in[6];
  const float* W2   = (const float*)d_in[7];
  const float* b2   = (const float*)d_in[8];
  const float* Wlin = (const float*)d_in[9];
  const float* blin = (const float*)d_in[10];

  const int N = in_sizes[0] / 128;
  const int E = in_sizes[4];
  const int Q = in_sizes[3] / 2;
  const int* u = ei;
  const int* v = ei + E;

  float* ws = (float*)d_ws;
  size_t off = 0;
  auto alloc = [&](size_t n) { float* p = ws + off; off += n; return p; };
  const size_t N64 = (size_t)N * 64;
  const size_t N128 = (size_t)N * 128;
  const size_t N256 = (size_t)N * 256;

  float2* cf = (float2*)alloc((size_t)2 * E * 2);                 // 8B-aligned
  unsigned long long* dc = (unsigned long long*)alloc((size_t)2 * N);
  int* src  = (int*)alloc((size_t)2 * E);
  float* P1  = alloc(N128);
  float* P2  = alloc(N128);
  float* Z   = alloc(N256);
  float* HAr = alloc(N64);
  float* HAi = alloc(N64);
  float* HBr = alloc(N64);
  float* HBi = alloc(N64);
  int* rp   = (int*)alloc(N + 1);
  int* nxt  = (int*)alloc(N);
  int* bsum = (int*)alloc(64);
  (void)ws_size; (void)n_in; (void)out_size;

  const int eb = (E + 255) / 256;
  const int mb = (N + 31) / 32;
  const int NB = (N + 1023) / 1024;
  const int gb = (N + 3) / 4;
  const int epb = (E + mb - 1) / mb;  // edges per GEMM block (~320)

  // --- dispatch 1: layer-1 GEMM with deg-atomic prefix slices ---
  hipMemsetAsync(dc, 0, (size_t)N * 8, stream);
  k_gemm_deg<128><<<mb, 256, 0, stream>>>(
      u, v, ew, dc, E, epb, real, imag, W1, b1, P1, P2, HAr, HAi, N);
  // --- graph structure ---
  k_scan1<<<NB, 256, 0, stream>>>(dc, rp, bsum, N);
  k_scan3<<<(N + 256) / 256, 256, 0, stream>>>(rp, nxt, bsum, N, 2 * E);
  k_scatter<<<eb, 256, 0, stream>>>(u, v, ew, dc, nxt, src, cf, E);

  // --- layer 1 sparse ---
  k_gU<<<gb, 256, 0, stream>>>(src, cf, rp, P2, P1, Z, N);
  k_gC<<<gb, 256, 0, stream>>>(src, cf, rp, Z, HAr, HAi, N);

  // --- layer 2 ---
  k_gemmF<64><<<mb, 256, 0, stream>>>(HAr, HAi, W2, b2, P1, P2, HBr, HBi, N);
  k_gU<<<gb, 256, 0, stream>>>(src, cf, rp, P2, P1, Z, N);
  k_gC<<<gb, 256, 0, stream>>>(src, cf, rp, Z, HBr, HBi, N);

  // --- queries ---
  k_query<<<(Q + 3) / 4, 256, 0, stream>>>(qe, HBr, HBi, Wlin, blin, (float*)d_out, Q);
}